// Round 9
// baseline (244.899 us; speedup 1.0000x reference)
//
#include <hip/hip_runtime.h>

typedef unsigned int u32;
typedef unsigned short u16;
typedef __attribute__((ext_vector_type(8))) short short8;   // 8 bf16 (4 VGPR)
typedef __attribute__((ext_vector_type(8))) unsigned short u16x8;
typedef __attribute__((ext_vector_type(4))) float f32x4;
typedef __attribute__((ext_vector_type(4))) unsigned short u16x4;

#define CAP 4864   // 256-node buckets: mean 4096 edges, sigma~64 -> +12 sigma
#define EPB 4096   // edges per staging block (391 blocks)

// ---------------------------------------------------------------------------
// bf16 helpers (RNE)
// ---------------------------------------------------------------------------
__device__ __forceinline__ u16 f2bf(float f) {
  u32 u = __builtin_bit_cast(u32, f);
  u32 r = (u + 0x7fffu + ((u >> 16) & 1u)) >> 16;
  return (u16)r;
}
__device__ __forceinline__ float bf2f(u32 lo16) {
  return __builtin_bit_cast(float, lo16 << 16);
}

// ---------------------------------------------------------------------------
// Dropout mask = bit-exact JAX threefry (partitionable mode — VERIFIED round 1)
// ---------------------------------------------------------------------------
__device__ __forceinline__ void threefry2x32(u32 k0, u32 k1, u32 x0, u32 x1,
                                             u32& y0, u32& y1) {
  const u32 ks2 = k0 ^ k1 ^ 0x1BD11BDAu;
#define TFR(r) { x0 += x1; x1 = (x1 << (r)) | (x1 >> (32 - (r))); x1 ^= x0; }
  x0 += k0; x1 += k1;
  TFR(13) TFR(15) TFR(26) TFR(6)
  x0 += k1; x1 += ks2 + 1u;
  TFR(17) TFR(29) TFR(16) TFR(24)
  x0 += ks2; x1 += k0 + 2u;
  TFR(13) TFR(15) TFR(26) TFR(6)
  x0 += k0; x1 += k1 + 3u;
  TFR(17) TFR(29) TFR(16) TFR(24)
  x0 += k1; x1 += ks2 + 4u;
  TFR(13) TFR(15) TFR(26) TFR(6)
  x0 += ks2; x1 += k0 + 5u;
#undef TFR
  y0 = x0; y1 = x1;
}

__device__ __forceinline__ bool dropout_keep(u32 j) {
  u32 y0, y1;
  threefry2x32(0u, 42u, 0u, j, y0, y1);
  return ((y0 ^ y1) & 0x80000000u) == 0u;
}

// ---------------------------------------------------------------------------
// stage_edges (standalone, small LDS, many blocks): LDS hist over 256-node
// buckets -> per-bucket chunk reservation -> bucket-major ~contiguous writes.
// ---------------------------------------------------------------------------
__global__ __launch_bounds__(256) void stage_edges(
    const int* __restrict__ src, const int* __restrict__ dst,
    const float* __restrict__ ew, int* __restrict__ bcur,
    int2* __restrict__ staged, int E, int nb) {
  __shared__ int h[512];
  __shared__ int cb[512];
  const int t = threadIdx.x;
  for (int j = t; j < nb; j += 256) h[j] = 0;
  __syncthreads();
  const int base = blockIdx.x * EPB;
  const int end = min(base + EPB, E);
  for (int i = base + t; i < end; i += 256)
    atomicAdd(&h[(u32)dst[i] >> 8], 1);
  __syncthreads();
  for (int j = t; j < nb; j += 256) {
    cb[j] = h[j] ? atomicAdd(&bcur[j], h[j]) : 0;
    h[j] = 0;
  }
  __syncthreads();
  for (int i = base + t; i < end; i += 256) {
    int d = dst[i];
    int b = (u32)d >> 8;
    int loc = atomicAdd(&h[b], 1);
    int pos = cb[b] + loc;
    if (pos < CAP)  // overflow guard (never fires for this input)
      staged[(size_t)b * CAP + pos] =
          make_int2(src[i] | ((d & 255) << 23), __builtin_bit_cast(int, ew[i]));
  }
}

// ---------------------------------------------------------------------------
// bucket_sort: one block per 256-node bucket; one thread per node.
// LDS hist + scan -> rowinfo(start,len) with even (16B) row starts; scatter.
// ---------------------------------------------------------------------------
__global__ __launch_bounds__(256) void bucket_sort(
    const int2* __restrict__ staged, const int* __restrict__ bcur,
    int2* __restrict__ rowinfo, int2* __restrict__ epk, int N) {
  __shared__ int cnt[256];
  __shared__ int cur[256];
  __shared__ int sc[256];
  const int t = threadIdx.x;
  const int b = blockIdx.x;
  const int node0 = b << 8;
  const int nn = min(256, N - node0);
  const int ebase = b * CAP;
  const int ecnt = min(bcur[b], CAP);
  cnt[t] = 0;
  __syncthreads();
  for (int i = t; i < ecnt; i += 256)
    atomicAdd(&cnt[(u32)staged[ebase + i].x >> 23], 1);
  __syncthreads();
  int a = cnt[t];
  int pa = (a + 1) & ~1;  // even-padded length
  sc[t] = pa;
  __syncthreads();
  for (int off = 1; off < 256; off <<= 1) {
    int tmp = (t >= off) ? sc[t - off] : 0;
    __syncthreads();
    sc[t] += tmp;
    __syncthreads();
  }
  int excl = sc[t] - pa;
  cur[t] = ebase + excl;
  if (t < nn) rowinfo[node0 + t] = make_int2(ebase + excl, a);
  __syncthreads();
  for (int i = t; i < ecnt; i += 256) {
    int2 p = staged[ebase + i];
    int dl = (u32)p.x >> 23;
    int pos = atomicAdd(&cur[dl], 1);
    epk[pos] = make_int2(p.x & 0x7fffff, p.y);
  }
}

// ---------------------------------------------------------------------------
// CSR spmm F=128: one node per HALF-wave, 8B/lane gathers, unroll 16.
// FMA chain order sequential in e — bit-identical across rounds.
// ---------------------------------------------------------------------------
#define F128_FMA2(VA, VB, W0, W1)                      \
  { float w0 = __builtin_bit_cast(float, W0);          \
    float w1 = __builtin_bit_cast(float, W1);          \
    a0 = fmaf(bf2f((VA).x & 0xffffu), w0, a0);         \
    a1 = fmaf(bf2f((VA).x >> 16), w0, a1);             \
    a2 = fmaf(bf2f((VA).y & 0xffffu), w0, a2);         \
    a3 = fmaf(bf2f((VA).y >> 16), w0, a3);             \
    a0 = fmaf(bf2f((VB).x & 0xffffu), w1, a0);         \
    a1 = fmaf(bf2f((VB).x >> 16), w1, a1);             \
    a2 = fmaf(bf2f((VB).y & 0xffffu), w1, a2);         \
    a3 = fmaf(bf2f((VB).y >> 16), w1, a3); }

__global__ __launch_bounds__(256) void spmm_csr_f128_bf16(
    const u16* __restrict__ V, const int2* __restrict__ epk,
    const int2* __restrict__ rowinfo, u16* __restrict__ out, int N) {
  int node = blockIdx.x * 8 + (threadIdx.x >> 5);
  if (node >= N) return;
  int l32 = threadIdx.x & 31;
  int2 ri = rowinfo[node];
  int e = ri.x, end = ri.x + ri.y;
  float a0 = 0.f, a1 = 0.f, a2 = 0.f, a3 = 0.f;
  for (; e + 16 <= end; e += 16) {
    int4 pp[8];
#pragma unroll
    for (int k = 0; k < 8; ++k)
      pp[k] = reinterpret_cast<const int4*>(epk + e)[k];
    uint2 v[16];
#pragma unroll
    for (int k = 0; k < 8; ++k) {
      v[2 * k] = reinterpret_cast<const uint2*>(V + (size_t)pp[k].x * 128)[l32];
      v[2 * k + 1] = reinterpret_cast<const uint2*>(V + (size_t)pp[k].z * 128)[l32];
    }
#pragma unroll
    for (int k = 0; k < 8; ++k)
      F128_FMA2(v[2 * k], v[2 * k + 1], pp[k].y, pp[k].w);
  }
  for (; e + 4 <= end; e += 4) {
    int4 pp[2];
#pragma unroll
    for (int k = 0; k < 2; ++k)
      pp[k] = reinterpret_cast<const int4*>(epk + e)[k];
    uint2 v[4];
#pragma unroll
    for (int k = 0; k < 2; ++k) {
      v[2 * k] = reinterpret_cast<const uint2*>(V + (size_t)pp[k].x * 128)[l32];
      v[2 * k + 1] = reinterpret_cast<const uint2*>(V + (size_t)pp[k].z * 128)[l32];
    }
#pragma unroll
    for (int k = 0; k < 2; ++k)
      F128_FMA2(v[2 * k], v[2 * k + 1], pp[k].y, pp[k].w);
  }
  for (; e < end; ++e) {
    int2 p = epk[e];
    uint2 v = reinterpret_cast<const uint2*>(V + (size_t)p.x * 128)[l32];
    float w = __builtin_bit_cast(float, p.y);
    a0 = fmaf(bf2f(v.x & 0xffffu), w, a0);
    a1 = fmaf(bf2f(v.x >> 16), w, a1);
    a2 = fmaf(bf2f(v.y & 0xffffu), w, a2);
    a3 = fmaf(bf2f(v.y >> 16), w, a3);
  }
  uint2 o;
  o.x = (u32)f2bf(a0) | ((u32)f2bf(a1) << 16);
  o.y = (u32)f2bf(a2) | ((u32)f2bf(a3) << 16);
  reinterpret_cast<uint2*>(out + (size_t)node * 128)[l32] = o;
}

// ---------------------------------------------------------------------------
// CSR spmm F=64: one node per QUARTER-wave (16 lanes x 8B), unroll 16,
// b2 folded into accumulator init.
// ---------------------------------------------------------------------------
__global__ __launch_bounds__(256) void spmm_csr_f64_bias(
    const u16* __restrict__ V, const int2* __restrict__ epk,
    const int2* __restrict__ rowinfo, const float* __restrict__ b2,
    float* __restrict__ out, int N) {
  int node = blockIdx.x * 16 + (threadIdx.x >> 4);
  if (node >= N) return;
  int l16 = threadIdx.x & 15;
  int2 ri = rowinfo[node];
  int e = ri.x, end = ri.x + ri.y;
  float4 bb = reinterpret_cast<const float4*>(b2)[l16];
  float a0 = bb.x, a1 = bb.y, a2 = bb.z, a3 = bb.w;
  for (; e + 16 <= end; e += 16) {
    int4 pp[8];
#pragma unroll
    for (int k = 0; k < 8; ++k)
      pp[k] = reinterpret_cast<const int4*>(epk + e)[k];
    uint2 v[16];
#pragma unroll
    for (int k = 0; k < 8; ++k) {
      v[2 * k] = reinterpret_cast<const uint2*>(V + (size_t)pp[k].x * 64)[l16];
      v[2 * k + 1] = reinterpret_cast<const uint2*>(V + (size_t)pp[k].z * 64)[l16];
    }
#pragma unroll
    for (int k = 0; k < 8; ++k)
      F128_FMA2(v[2 * k], v[2 * k + 1], pp[k].y, pp[k].w);
  }
  for (; e + 4 <= end; e += 4) {
    int4 pp[2];
#pragma unroll
    for (int k = 0; k < 2; ++k)
      pp[k] = reinterpret_cast<const int4*>(epk + e)[k];
    uint2 v[4];
#pragma unroll
    for (int k = 0; k < 2; ++k) {
      v[2 * k] = reinterpret_cast<const uint2*>(V + (size_t)pp[k].x * 64)[l16];
      v[2 * k + 1] = reinterpret_cast<const uint2*>(V + (size_t)pp[k].z * 64)[l16];
    }
#pragma unroll
    for (int k = 0; k < 2; ++k)
      F128_FMA2(v[2 * k], v[2 * k + 1], pp[k].y, pp[k].w);
  }
  for (; e < end; ++e) {
    int2 p = epk[e];
    uint2 v = reinterpret_cast<const uint2*>(V + (size_t)p.x * 64)[l16];
    float w = __builtin_bit_cast(float, p.y);
    a0 = fmaf(bf2f(v.x & 0xffffu), w, a0);
    a1 = fmaf(bf2f(v.x >> 16), w, a1);
    a2 = fmaf(bf2f(v.y & 0xffffu), w, a2);
    a3 = fmaf(bf2f(v.y >> 16), w, a3);
  }
  reinterpret_cast<float4*>(out + (size_t)node * 64)[l16] =
      make_float4(a0, a1, a2, a3);
}

// ---------------------------------------------------------------------------
// GEMM A (MFMA bf16): y[N,128](bf16) = x @ W1 — verified round 3
// ---------------------------------------------------------------------------
__global__ __launch_bounds__(256) void gemm_xw1_mfma(
    const float* __restrict__ X, const float* __restrict__ W,
    u16* __restrict__ Y, int N) {
  __shared__ short As[128 * 128];
  __shared__ short Bs[128 * 128];
  const int t = threadIdx.x;
  const int row0 = blockIdx.x << 7;

  for (int i = t; i < 128 * 32; i += 256) {
    int m = i >> 5, k4 = i & 31;
    int r = row0 + m;
    float4 v = make_float4(0.f, 0.f, 0.f, 0.f);
    if (r < N) v = reinterpret_cast<const float4*>(X)[(size_t)r * 32 + k4];
    u16x4 b;
    b.x = f2bf(v.x); b.y = f2bf(v.y); b.z = f2bf(v.z); b.w = f2bf(v.w);
    int off = (m * 128 + (k4 << 2)) ^ ((m & 7) << 3);
    *reinterpret_cast<u16x4*>(&As[off]) = b;
  }
  for (int i = t; i < 128 * 32; i += 256) {
    int k = i >> 5, n4 = i & 31;
    float4 v = reinterpret_cast<const float4*>(W)[(size_t)k * 32 + n4];
    int c0 = n4 << 2;
    Bs[(((c0 + 0) * 128 + k)) ^ (((c0 + 0) & 7) << 3)] = (short)f2bf(v.x);
    Bs[(((c0 + 1) * 128 + k)) ^ (((c0 + 1) & 7) << 3)] = (short)f2bf(v.y);
    Bs[(((c0 + 2) * 128 + k)) ^ (((c0 + 2) & 7) << 3)] = (short)f2bf(v.z);
    Bs[(((c0 + 3) * 128 + k)) ^ (((c0 + 3) & 7) << 3)] = (short)f2bf(v.w);
  }
  __syncthreads();

  const int wid = t >> 6, lane = t & 63;
  const int wr = (wid >> 1) * 64, wc = (wid & 1) * 64;
  const int l15 = lane & 15, lk = (lane >> 4) * 8;

  f32x4 acc[4][4];
#pragma unroll
  for (int m = 0; m < 4; ++m)
#pragma unroll
    for (int n = 0; n < 4; ++n) acc[m][n] = (f32x4)(0.f);

#pragma unroll
  for (int kk = 0; kk < 4; ++kk) {
    const int kb = kk * 32 + lk;
    short8 a[4], b[4];
#pragma unroll
    for (int m = 0; m < 4; ++m) {
      int row = wr + m * 16 + l15;
      a[m] = *reinterpret_cast<const short8*>(&As[(row * 128 + kb) ^ ((row & 7) << 3)]);
    }
#pragma unroll
    for (int n = 0; n < 4; ++n) {
      int col = wc + n * 16 + l15;
      b[n] = *reinterpret_cast<const short8*>(&Bs[(col * 128 + kb) ^ ((col & 7) << 3)]);
    }
#pragma unroll
    for (int m = 0; m < 4; ++m)
#pragma unroll
      for (int n = 0; n < 4; ++n)
        acc[m][n] = __builtin_amdgcn_mfma_f32_16x16x32_bf16(a[m], b[n], acc[m][n], 0, 0, 0);
  }

#pragma unroll
  for (int m = 0; m < 4; ++m) {
    int rbase = row0 + wr + m * 16 + (lane >> 4) * 4;
#pragma unroll
    for (int n = 0; n < 4; ++n) {
      int col = wc + n * 16 + l15;
#pragma unroll
      for (int r = 0; r < 4; ++r) {
        int row = rbase + r;
        if (row < N) Y[(size_t)row * 128 + col] = f2bf(acc[m][n][r]);
      }
    }
  }
}

// ---------------------------------------------------------------------------
// GEMM B (MFMA bf16, fused): h3[N,64] = dropout(relu(h1 + b1)) @ W2
// tile 64x64 (LDS 32KB -> 5 blocks/CU), 4 waves x 16 rows each.
// ---------------------------------------------------------------------------
__global__ __launch_bounds__(256) void gemm_h_w2_mfma(
    const u16* __restrict__ H, const float* __restrict__ bias1,
    const float* __restrict__ W2, u16* __restrict__ O, int N) {
  __shared__ short As[64 * 128];  // 16 KB
  __shared__ short Bs[64 * 128];  // 16 KB (transposed: [n][k])
  const int t = threadIdx.x;
  const int row0 = blockIdx.x << 6;

  for (int i = t; i < 128 * 16; i += 256) {
    int k = i >> 4, n4 = i & 15;
    float4 v = reinterpret_cast<const float4*>(W2)[(size_t)k * 16 + n4];
    int c0 = n4 << 2;
    Bs[(((c0 + 0) * 128 + k)) ^ (((c0 + 0) & 7) << 3)] = (short)f2bf(v.x);
    Bs[(((c0 + 1) * 128 + k)) ^ (((c0 + 1) & 7) << 3)] = (short)f2bf(v.y);
    Bs[(((c0 + 2) * 128 + k)) ^ (((c0 + 2) & 7) << 3)] = (short)f2bf(v.z);
    Bs[(((c0 + 3) * 128 + k)) ^ (((c0 + 3) & 7) << 3)] = (short)f2bf(v.w);
  }

  for (int i = t; i < 64 * 16; i += 256) {
    int m = i >> 4, g = i & 15;
    int r = row0 + m;
    int c0 = g << 3;
    u16x8 o = (u16x8)(0);
    if (r < N) {
      u16x8 v = *reinterpret_cast<const u16x8*>(H + (size_t)r * 128 + c0);
      float4 b0 = reinterpret_cast<const float4*>(bias1)[g * 2];
      float4 b1v = reinterpret_cast<const float4*>(bias1)[g * 2 + 1];
      float bb[8] = {b0.x, b0.y, b0.z, b0.w, b1v.x, b1v.y, b1v.z, b1v.w};
      u32 base = (u32)r * 128u + (u32)c0;
#pragma unroll
      for (int e = 0; e < 8; ++e) {
        float z = fmaxf(bf2f((u16)v[e]) + bb[e], 0.f);
        o[e] = dropout_keep(base + e) ? f2bf(z + z) : (u16)0;
      }
    }
    *reinterpret_cast<u16x8*>(&As[(m * 128 + c0) ^ ((m & 7) << 3)]) = o;
  }
  __syncthreads();

  const int wid = t >> 6, lane = t & 63;
  const int wr = wid * 16;
  const int l15 = lane & 15, lk = (lane >> 4) * 8;

  f32x4 acc[4];
#pragma unroll
  for (int n = 0; n < 4; ++n) acc[n] = (f32x4)(0.f);

#pragma unroll
  for (int kk = 0; kk < 4; ++kk) {
    const int kb = kk * 32 + lk;
    int row = wr + l15;
    short8 a = *reinterpret_cast<const short8*>(&As[(row * 128 + kb) ^ ((row & 7) << 3)]);
    short8 b[4];
#pragma unroll
    for (int n = 0; n < 4; ++n) {
      int col = n * 16 + l15;
      b[n] = *reinterpret_cast<const short8*>(&Bs[(col * 128 + kb) ^ ((col & 7) << 3)]);
    }
#pragma unroll
    for (int n = 0; n < 4; ++n)
      acc[n] = __builtin_amdgcn_mfma_f32_16x16x32_bf16(a, b[n], acc[n], 0, 0, 0);
  }

  {
    int rbase = row0 + wr + (lane >> 4) * 4;
#pragma unroll
    for (int n = 0; n < 4; ++n) {
      int col = n * 16 + l15;
#pragma unroll
      for (int r = 0; r < 4; ++r) {
        int row = rbase + r;
        if (row < N) O[(size_t)row * 64 + col] = f2bf(acc[n][r]);
      }
    }
  }
}

// ---------------------------------------------------------------------------
// Pipeline:
//   memset bcur ; stage_edges ; gemmA ; bucket_sort ;
//   spmm128 -> h1 ; gemmB -> h3 ; spmm64(+b2) -> out
// ---------------------------------------------------------------------------
extern "C" void kernel_launch(void* const* d_in, const int* in_sizes, int n_in,
                              void* d_out, int out_size, void* d_ws, size_t ws_size,
                              hipStream_t stream) {
  const float* x  = (const float*)d_in[0];
  const float* ew = (const float*)d_in[1];
  const float* W1 = (const float*)d_in[2];
  const float* b1 = (const float*)d_in[3];
  const float* W2 = (const float*)d_in[4];
  const float* b2 = (const float*)d_in[5];
  const int*   src = (const int*)d_in[6];
  const int*   dst = (const int*)d_in[7];
  const int N = in_sizes[0] / 128;
  const int E = in_sizes[1];
  float* out = (float*)d_out;

  const int nb = (N + 255) >> 8;  // 256-node buckets (391 for N=100000)

  // workspace layout
  u16*   h1      = (u16*)d_ws;                       // N*128 bf16
  u16*   y       = h1 + (size_t)N * 128;             // N*128 bf16 (reused as h3)
  u16*   h3      = y;
  int2*  staged  = (int2*)(y + (size_t)N * 128);     // nb*CAP * 8B
  int2*  epk     = staged + (size_t)nb * CAP;        // nb*CAP * 8B
  int2*  rowinfo = epk + (size_t)nb * CAP;           // N * 8B
  int*   bcur    = (int*)(rowinfo + N + 4);          // nb (relative cursors)

  const int cBlocks = (E + EPB - 1) / EPB;
  const int gBlocks = (N + 127) / 128;

  hipMemsetAsync(bcur, 0, (size_t)nb * sizeof(int), stream);
  stage_edges<<<cBlocks, 256, 0, stream>>>(src, dst, ew, bcur, staged, E, nb);
  gemm_xw1_mfma<<<gBlocks, 256, 0, stream>>>(x, W1, y, N);
  bucket_sort<<<nb, 256, 0, stream>>>(staged, bcur, rowinfo, epk, N);
  spmm_csr_f128_bf16<<<(N + 7) / 8, 256, 0, stream>>>(y, epk, rowinfo, h1, N);
  gemm_h_w2_mfma<<<(N + 63) / 64, 256, 0, stream>>>(h1, b1, W2, h3, N);
  spmm_csr_f64_bias<<<(N + 15) / 16, 256, 0, stream>>>(h3, epk, rowinfo, b2, out, N);
}

// Round 12
// 234.680 us; speedup vs baseline: 1.0435x; 1.0435x over previous
//
#include <hip/hip_runtime.h>

typedef unsigned int u32;
typedef unsigned short u16;
typedef __attribute__((ext_vector_type(8))) short short8;   // 8 bf16 (4 VGPR)
typedef __attribute__((ext_vector_type(8))) unsigned short u16x8;
typedef __attribute__((ext_vector_type(4))) float f32x4;
typedef __attribute__((ext_vector_type(4))) unsigned short u16x4;

#define CAP 4864   // 256-node buckets: mean 4096 edges, sigma~64 -> +12 sigma
#define EPB 4096   // edges per staging block (391 blocks)

// ---------------------------------------------------------------------------
// bf16 helpers (RNE)
// ---------------------------------------------------------------------------
__device__ __forceinline__ u16 f2bf(float f) {
  u32 u = __builtin_bit_cast(u32, f);
  u32 r = (u + 0x7fffu + ((u >> 16) & 1u)) >> 16;
  return (u16)r;
}
__device__ __forceinline__ float bf2f(u32 lo16) {
  return __builtin_bit_cast(float, lo16 << 16);
}

// ---------------------------------------------------------------------------
// Dropout mask = bit-exact JAX threefry (partitionable mode — VERIFIED round 1)
// ---------------------------------------------------------------------------
__device__ __forceinline__ void threefry2x32(u32 k0, u32 k1, u32 x0, u32 x1,
                                             u32& y0, u32& y1) {
  const u32 ks2 = k0 ^ k1 ^ 0x1BD11BDAu;
#define TFR(r) { x0 += x1; x1 = (x1 << (r)) | (x1 >> (32 - (r))); x1 ^= x0; }
  x0 += k0; x1 += k1;
  TFR(13) TFR(15) TFR(26) TFR(6)
  x0 += k1; x1 += ks2 + 1u;
  TFR(17) TFR(29) TFR(16) TFR(24)
  x0 += ks2; x1 += k0 + 2u;
  TFR(13) TFR(15) TFR(26) TFR(6)
  x0 += k0; x1 += k1 + 3u;
  TFR(17) TFR(29) TFR(16) TFR(24)
  x0 += k1; x1 += ks2 + 4u;
  TFR(13) TFR(15) TFR(26) TFR(6)
  x0 += ks2; x1 += k0 + 5u;
#undef TFR
  y0 = x0; y1 = x1;
}

__device__ __forceinline__ bool dropout_keep(u32 j) {
  u32 y0, y1;
  threefry2x32(0u, 42u, 0u, j, y0, y1);
  return ((y0 ^ y1) & 0x80000000u) == 0u;
}

// ---------------------------------------------------------------------------
// stage_edges: LDS hist over 256-node buckets -> chunk reservation ->
// bucket-major ~contiguous writes of (src | dstlocal<<23, ew).  [verified r9]
// ---------------------------------------------------------------------------
__global__ __launch_bounds__(256) void stage_edges(
    const int* __restrict__ src, const int* __restrict__ dst,
    const float* __restrict__ ew, int* __restrict__ bcur,
    int2* __restrict__ staged, int E, int nb) {
  __shared__ int h[512];
  __shared__ int cb[512];
  const int t = threadIdx.x;
  for (int j = t; j < nb; j += 256) h[j] = 0;
  __syncthreads();
  const int base = blockIdx.x * EPB;
  const int end = min(base + EPB, E);
  for (int i = base + t; i < end; i += 256)
    atomicAdd(&h[(u32)dst[i] >> 8], 1);
  __syncthreads();
  for (int j = t; j < nb; j += 256) {
    cb[j] = h[j] ? atomicAdd(&bcur[j], h[j]) : 0;
    h[j] = 0;
  }
  __syncthreads();
  for (int i = base + t; i < end; i += 256) {
    int d = dst[i];
    int b = (u32)d >> 8;
    int loc = atomicAdd(&h[b], 1);
    int pos = cb[b] + loc;
    if (pos < CAP)  // overflow guard (never fires for this input)
      staged[(size_t)b * CAP + pos] =
          make_int2(src[i] | ((d & 255) << 23), __builtin_bit_cast(int, ew[i]));
  }
}

// ---------------------------------------------------------------------------
// bucket_sort: one block per 256-node bucket; one thread per node. [verified r9]
// ---------------------------------------------------------------------------
__global__ __launch_bounds__(256) void bucket_sort(
    const int2* __restrict__ staged, const int* __restrict__ bcur,
    int2* __restrict__ rowinfo, int2* __restrict__ epk, int N) {
  __shared__ int cnt[256];
  __shared__ int cur[256];
  __shared__ int sc[256];
  const int t = threadIdx.x;
  const int b = blockIdx.x;
  const int node0 = b << 8;
  const int nn = min(256, N - node0);
  const int ebase = b * CAP;
  const int ecnt = min(bcur[b], CAP);
  cnt[t] = 0;
  __syncthreads();
  for (int i = t; i < ecnt; i += 256)
    atomicAdd(&cnt[(u32)staged[ebase + i].x >> 23], 1);
  __syncthreads();
  int a = cnt[t];
  int pa = (a + 1) & ~1;  // even-padded length
  sc[t] = pa;
  __syncthreads();
  for (int off = 1; off < 256; off <<= 1) {
    int tmp = (t >= off) ? sc[t - off] : 0;
    __syncthreads();
    sc[t] += tmp;
    __syncthreads();
  }
  int excl = sc[t] - pa;
  cur[t] = ebase + excl;
  if (t < nn) rowinfo[node0 + t] = make_int2(ebase + excl, a);
  __syncthreads();
  for (int i = t; i < ecnt; i += 256) {
    int2 p = staged[ebase + i];
    int dl = (u32)p.x >> 23;
    int pos = atomicAdd(&cur[dl], 1);
    epk[pos] = make_int2(p.x & 0x7fffff, p.y);
  }
}

// ---------------------------------------------------------------------------
// shared FMA helper: 2 edges x 4 bf16 features into a0..a3 (fp32)
// ---------------------------------------------------------------------------
#define F128_FMA2(VA, VB, W0, W1)                      \
  { float w0 = __builtin_bit_cast(float, W0);          \
    float w1 = __builtin_bit_cast(float, W1);          \
    a0 = fmaf(bf2f((VA).x & 0xffffu), w0, a0);         \
    a1 = fmaf(bf2f((VA).x >> 16), w0, a1);             \
    a2 = fmaf(bf2f((VA).y & 0xffffu), w0, a2);         \
    a3 = fmaf(bf2f((VA).y >> 16), w0, a3);             \
    a0 = fmaf(bf2f((VB).x & 0xffffu), w1, a0);         \
    a1 = fmaf(bf2f((VB).x >> 16), w1, a1);             \
    a2 = fmaf(bf2f((VB).y & 0xffffu), w1, a2);         \
    a3 = fmaf(bf2f((VB).y >> 16), w1, a3); }

// ---------------------------------------------------------------------------
// CSR spmm F=128: one node per HALF-wave, 8B/lane gathers, UNROLL 8.
// [verified r7 — 60us @ occ 70%]  bf16 gather / fp32 acc / bf16 store.
// ---------------------------------------------------------------------------
__global__ __launch_bounds__(256) void spmm_csr_f128_bf16(
    const u16* __restrict__ V, const int2* __restrict__ epk,
    const int2* __restrict__ rowinfo, u16* __restrict__ out, int N) {
  int node = blockIdx.x * 8 + (threadIdx.x >> 5);
  if (node >= N) return;
  int l32 = threadIdx.x & 31;
  int2 ri = rowinfo[node];
  int e = ri.x, end = ri.x + ri.y;
  float a0 = 0.f, a1 = 0.f, a2 = 0.f, a3 = 0.f;
  for (; e + 8 <= end; e += 8) {
    int4 pp[4];
#pragma unroll
    for (int k = 0; k < 4; ++k)
      pp[k] = reinterpret_cast<const int4*>(epk + e)[k];
    uint2 v[8];
#pragma unroll
    for (int k = 0; k < 4; ++k) {
      v[2 * k] = reinterpret_cast<const uint2*>(V + (size_t)pp[k].x * 128)[l32];
      v[2 * k + 1] = reinterpret_cast<const uint2*>(V + (size_t)pp[k].z * 128)[l32];
    }
#pragma unroll
    for (int k = 0; k < 4; ++k)
      F128_FMA2(v[2 * k], v[2 * k + 1], pp[k].y, pp[k].w);
  }
  if (e + 4 <= end) {
    int4 pp[2];
#pragma unroll
    for (int k = 0; k < 2; ++k)
      pp[k] = reinterpret_cast<const int4*>(epk + e)[k];
    uint2 v[4];
#pragma unroll
    for (int k = 0; k < 2; ++k) {
      v[2 * k] = reinterpret_cast<const uint2*>(V + (size_t)pp[k].x * 128)[l32];
      v[2 * k + 1] = reinterpret_cast<const uint2*>(V + (size_t)pp[k].z * 128)[l32];
    }
#pragma unroll
    for (int k = 0; k < 2; ++k)
      F128_FMA2(v[2 * k], v[2 * k + 1], pp[k].y, pp[k].w);
    e += 4;
  }
  for (; e < end; ++e) {
    int2 p = epk[e];
    uint2 v = reinterpret_cast<const uint2*>(V + (size_t)p.x * 128)[l32];
    float w = __builtin_bit_cast(float, p.y);
    a0 = fmaf(bf2f(v.x & 0xffffu), w, a0);
    a1 = fmaf(bf2f(v.x >> 16), w, a1);
    a2 = fmaf(bf2f(v.y & 0xffffu), w, a2);
    a3 = fmaf(bf2f(v.y >> 16), w, a3);
  }
  uint2 o;
  o.x = (u32)f2bf(a0) | ((u32)f2bf(a1) << 16);
  o.y = (u32)f2bf(a2) | ((u32)f2bf(a3) << 16);
  reinterpret_cast<uint2*>(out + (size_t)node * 128)[l32] = o;
}

// ---------------------------------------------------------------------------
// CSR spmm F=64: one node per QUARTER-wave (16 lanes x 8B), unroll 8,
// b2 folded into accumulator init.  [verified r7]
// ---------------------------------------------------------------------------
__global__ __launch_bounds__(256) void spmm_csr_f64_bias(
    const u16* __restrict__ V, const int2* __restrict__ epk,
    const int2* __restrict__ rowinfo, const float* __restrict__ b2,
    float* __restrict__ out, int N) {
  int node = blockIdx.x * 16 + (threadIdx.x >> 4);
  if (node >= N) return;
  int l16 = threadIdx.x & 15;
  int2 ri = rowinfo[node];
  int e = ri.x, end = ri.x + ri.y;
  float4 bb = reinterpret_cast<const float4*>(b2)[l16];
  float a0 = bb.x, a1 = bb.y, a2 = bb.z, a3 = bb.w;
  for (; e + 8 <= end; e += 8) {
    int4 pp[4];
#pragma unroll
    for (int k = 0; k < 4; ++k)
      pp[k] = reinterpret_cast<const int4*>(epk + e)[k];
    uint2 v[8];
#pragma unroll
    for (int k = 0; k < 4; ++k) {
      v[2 * k] = reinterpret_cast<const uint2*>(V + (size_t)pp[k].x * 64)[l16];
      v[2 * k + 1] = reinterpret_cast<const uint2*>(V + (size_t)pp[k].z * 64)[l16];
    }
#pragma unroll
    for (int k = 0; k < 4; ++k)
      F128_FMA2(v[2 * k], v[2 * k + 1], pp[k].y, pp[k].w);
  }
  for (; e < end; ++e) {
    int2 p = epk[e];
    uint2 v = reinterpret_cast<const uint2*>(V + (size_t)p.x * 64)[l16];
    float w = __builtin_bit_cast(float, p.y);
    a0 = fmaf(bf2f(v.x & 0xffffu), w, a0);
    a1 = fmaf(bf2f(v.x >> 16), w, a1);
    a2 = fmaf(bf2f(v.y & 0xffffu), w, a2);
    a3 = fmaf(bf2f(v.y >> 16), w, a3);
  }
  reinterpret_cast<float4*>(out + (size_t)node * 64)[l16] =
      make_float4(a0, a1, a2, a3);
}

// ---------------------------------------------------------------------------
// GEMM A (MFMA bf16): y[N,128](bf16) = x @ W1 — verified round 3
// ---------------------------------------------------------------------------
__global__ __launch_bounds__(256) void gemm_xw1_mfma(
    const float* __restrict__ X, const float* __restrict__ W,
    u16* __restrict__ Y, int N) {
  __shared__ short As[128 * 128];
  __shared__ short Bs[128 * 128];
  const int t = threadIdx.x;
  const int row0 = blockIdx.x << 7;

  for (int i = t; i < 128 * 32; i += 256) {
    int m = i >> 5, k4 = i & 31;
    int r = row0 + m;
    float4 v = make_float4(0.f, 0.f, 0.f, 0.f);
    if (r < N) v = reinterpret_cast<const float4*>(X)[(size_t)r * 32 + k4];
    u16x4 b;
    b.x = f2bf(v.x); b.y = f2bf(v.y); b.z = f2bf(v.z); b.w = f2bf(v.w);
    int off = (m * 128 + (k4 << 2)) ^ ((m & 7) << 3);
    *reinterpret_cast<u16x4*>(&As[off]) = b;
  }
  for (int i = t; i < 128 * 32; i += 256) {
    int k = i >> 5, n4 = i & 31;
    float4 v = reinterpret_cast<const float4*>(W)[(size_t)k * 32 + n4];
    int c0 = n4 << 2;
    Bs[(((c0 + 0) * 128 + k)) ^ (((c0 + 0) & 7) << 3)] = (short)f2bf(v.x);
    Bs[(((c0 + 1) * 128 + k)) ^ (((c0 + 1) & 7) << 3)] = (short)f2bf(v.y);
    Bs[(((c0 + 2) * 128 + k)) ^ (((c0 + 2) & 7) << 3)] = (short)f2bf(v.z);
    Bs[(((c0 + 3) * 128 + k)) ^ (((c0 + 3) & 7) << 3)] = (short)f2bf(v.w);
  }
  __syncthreads();

  const int wid = t >> 6, lane = t & 63;
  const int wr = (wid >> 1) * 64, wc = (wid & 1) * 64;
  const int l15 = lane & 15, lk = (lane >> 4) * 8;

  f32x4 acc[4][4];
#pragma unroll
  for (int m = 0; m < 4; ++m)
#pragma unroll
    for (int n = 0; n < 4; ++n) acc[m][n] = (f32x4)(0.f);

#pragma unroll
  for (int kk = 0; kk < 4; ++kk) {
    const int kb = kk * 32 + lk;
    short8 a[4], b[4];
#pragma unroll
    for (int m = 0; m < 4; ++m) {
      int row = wr + m * 16 + l15;
      a[m] = *reinterpret_cast<const short8*>(&As[(row * 128 + kb) ^ ((row & 7) << 3)]);
    }
#pragma unroll
    for (int n = 0; n < 4; ++n) {
      int col = wc + n * 16 + l15;
      b[n] = *reinterpret_cast<const short8*>(&Bs[(col * 128 + kb) ^ ((col & 7) << 3)]);
    }
#pragma unroll
    for (int m = 0; m < 4; ++m)
#pragma unroll
      for (int n = 0; n < 4; ++n)
        acc[m][n] = __builtin_amdgcn_mfma_f32_16x16x32_bf16(a[m], b[n], acc[m][n], 0, 0, 0);
  }

#pragma unroll
  for (int m = 0; m < 4; ++m) {
    int rbase = row0 + wr + m * 16 + (lane >> 4) * 4;
#pragma unroll
    for (int n = 0; n < 4; ++n) {
      int col = wc + n * 16 + l15;
#pragma unroll
      for (int r = 0; r < 4; ++r) {
        int row = rbase + r;
        if (row < N) Y[(size_t)row * 128 + col] = f2bf(acc[m][n][r]);
      }
    }
  }
}

// ---------------------------------------------------------------------------
// GEMM B (MFMA bf16, fused epilogue): h3[N,64] = dropout(relu(h1 + b1)) @ W2
// tile 64x64 (LDS 32KB -> 5 blocks/CU), 4 waves x 16 rows. [verified r9]
// ---------------------------------------------------------------------------
__global__ __launch_bounds__(256) void gemm_h_w2_mfma(
    const u16* __restrict__ H, const float* __restrict__ bias1,
    const float* __restrict__ W2, u16* __restrict__ O, int N) {
  __shared__ short As[64 * 128];  // 16 KB
  __shared__ short Bs[64 * 128];  // 16 KB (transposed: [n][k])
  const int t = threadIdx.x;
  const int row0 = blockIdx.x << 6;

  for (int i = t; i < 128 * 16; i += 256) {
    int k = i >> 4, n4 = i & 15;
    float4 v = reinterpret_cast<const float4*>(W2)[(size_t)k * 16 + n4];
    int c0 = n4 << 2;
    Bs[(((c0 + 0) * 128 + k)) ^ (((c0 + 0) & 7) << 3)] = (short)f2bf(v.x);
    Bs[(((c0 + 1) * 128 + k)) ^ (((c0 + 1) & 7) << 3)] = (short)f2bf(v.y);
    Bs[(((c0 + 2) * 128 + k)) ^ (((c0 + 2) & 7) << 3)] = (short)f2bf(v.z);
    Bs[(((c0 + 3) * 128 + k)) ^ (((c0 + 3) & 7) << 3)] = (short)f2bf(v.w);
  }

  for (int i = t; i < 64 * 16; i += 256) {
    int m = i >> 4, g = i & 15;
    int r = row0 + m;
    int c0 = g << 3;
    u16x8 o = (u16x8)(0);
    if (r < N) {
      u16x8 v = *reinterpret_cast<const u16x8*>(H + (size_t)r * 128 + c0);
      float4 b0 = reinterpret_cast<const float4*>(bias1)[g * 2];
      float4 b1v = reinterpret_cast<const float4*>(bias1)[g * 2 + 1];
      float bb[8] = {b0.x, b0.y, b0.z, b0.w, b1v.x, b1v.y, b1v.z, b1v.w};
      u32 base = (u32)r * 128u + (u32)c0;
#pragma unroll
      for (int e = 0; e < 8; ++e) {
        float z = fmaxf(bf2f((u16)v[e]) + bb[e], 0.f);
        o[e] = dropout_keep(base + e) ? f2bf(z + z) : (u16)0;
      }
    }
    *reinterpret_cast<u16x8*>(&As[(m * 128 + c0) ^ ((m & 7) << 3)]) = o;
  }
  __syncthreads();

  const int wid = t >> 6, lane = t & 63;
  const int wr = wid * 16;
  const int l15 = lane & 15, lk = (lane >> 4) * 8;

  f32x4 acc[4];
#pragma unroll
  for (int n = 0; n < 4; ++n) acc[n] = (f32x4)(0.f);

#pragma unroll
  for (int kk = 0; kk < 4; ++kk) {
    const int kb = kk * 32 + lk;
    int row = wr + l15;
    short8 a = *reinterpret_cast<const short8*>(&As[(row * 128 + kb) ^ ((row & 7) << 3)]);
    short8 b[4];
#pragma unroll
    for (int n = 0; n < 4; ++n) {
      int col = n * 16 + l15;
      b[n] = *reinterpret_cast<const short8*>(&Bs[(col * 128 + kb) ^ ((col & 7) << 3)]);
    }
#pragma unroll
    for (int n = 0; n < 4; ++n)
      acc[n] = __builtin_amdgcn_mfma_f32_16x16x32_bf16(a, b[n], acc[n], 0, 0, 0);
  }

  {
    int rbase = row0 + wr + (lane >> 4) * 4;
#pragma unroll
    for (int n = 0; n < 4; ++n) {
      int col = n * 16 + l15;
#pragma unroll
      for (int r = 0; r < 4; ++r) {
        int row = rbase + r;
        if (row < N) O[(size_t)row * 64 + col] = f2bf(acc[n][r]);
      }
    }
  }
}

// ---------------------------------------------------------------------------
// Pipeline (all-verified assembly):
//   memset bcur ; stage_edges ; gemmA ; bucket_sort ;
//   spmm128 -> h1(bf16) ; gemmB -> h3 ; spmm64(+b2) -> out
// ---------------------------------------------------------------------------
extern "C" void kernel_launch(void* const* d_in, const int* in_sizes, int n_in,
                              void* d_out, int out_size, void* d_ws, size_t ws_size,
                              hipStream_t stream) {
  const float* x  = (const float*)d_in[0];
  const float* ew = (const float*)d_in[1];
  const float* W1 = (const float*)d_in[2];
  const float* b1 = (const float*)d_in[3];
  const float* W2 = (const float*)d_in[4];
  const float* b2 = (const float*)d_in[5];
  const int*   src = (const int*)d_in[6];
  const int*   dst = (const int*)d_in[7];
  const int N = in_sizes[0] / 128;
  const int E = in_sizes[1];
  float* out = (float*)d_out;

  const int nb = (N + 255) >> 8;  // 256-node buckets (391 for N=100000)

  // workspace layout (r9-verified)
  u16*   h1      = (u16*)d_ws;                       // N*128 bf16
  u16*   y       = h1 + (size_t)N * 128;             // N*128 bf16 (reused as h3)
  u16*   h3      = y;
  int2*  staged  = (int2*)(y + (size_t)N * 128);     // nb*CAP * 8B
  int2*  epk     = staged + (size_t)nb * CAP;        // nb*CAP * 8B
  int2*  rowinfo = epk + (size_t)nb * CAP;           // N * 8B
  int*   bcur    = (int*)(rowinfo + N + 4);          // nb (relative cursors)

  const int cBlocks = (E + EPB - 1) / EPB;
  const int gBlocks = (N + 127) / 128;

  hipMemsetAsync(bcur, 0, (size_t)nb * sizeof(int), stream);
  stage_edges<<<cBlocks, 256, 0, stream>>>(src, dst, ew, bcur, staged, E, nb);
  gemm_xw1_mfma<<<gBlocks, 256, 0, stream>>>(x, W1, y, N);
  bucket_sort<<<nb, 256, 0, stream>>>(staged, bcur, rowinfo, epk, N);
  spmm_csr_f128_bf16<<<(N + 7) / 8, 256, 0, stream>>>(y, epk, rowinfo, h1, N);
  gemm_h_w2_mfma<<<(N + 63) / 64, 256, 0, stream>>>(h1, b1, W2, h3, N);
  spmm_csr_f64_bias<<<(N + 15) / 16, 256, 0, stream>>>(h3, epk, rowinfo, b2, out, N);
}

// Round 13
// 231.662 us; speedup vs baseline: 1.0571x; 1.0130x over previous
//
#include <hip/hip_runtime.h>

typedef unsigned int u32;
typedef unsigned short u16;
typedef __attribute__((ext_vector_type(8))) short short8;   // 8 bf16 (4 VGPR)
typedef __attribute__((ext_vector_type(8))) unsigned short u16x8;
typedef __attribute__((ext_vector_type(4))) float f32x4;
typedef __attribute__((ext_vector_type(4))) unsigned short u16x4;

#define CAP 4864   // 256-node buckets: mean 4096 edges, sigma~64 -> +12 sigma
#define EPB 4096   // edges per staging block (391 blocks)

// ---------------------------------------------------------------------------
// bf16 helpers (RNE)
// ---------------------------------------------------------------------------
__device__ __forceinline__ u16 f2bf(float f) {
  u32 u = __builtin_bit_cast(u32, f);
  u32 r = (u + 0x7fffu + ((u >> 16) & 1u)) >> 16;
  return (u16)r;
}
__device__ __forceinline__ float bf2f(u32 lo16) {
  return __builtin_bit_cast(float, lo16 << 16);
}

// ---------------------------------------------------------------------------
// Dropout mask = bit-exact JAX threefry (partitionable mode — VERIFIED round 1)
// ---------------------------------------------------------------------------
__device__ __forceinline__ void threefry2x32(u32 k0, u32 k1, u32 x0, u32 x1,
                                             u32& y0, u32& y1) {
  const u32 ks2 = k0 ^ k1 ^ 0x1BD11BDAu;
#define TFR(r) { x0 += x1; x1 = (x1 << (r)) | (x1 >> (32 - (r))); x1 ^= x0; }
  x0 += k0; x1 += k1;
  TFR(13) TFR(15) TFR(26) TFR(6)
  x0 += k1; x1 += ks2 + 1u;
  TFR(17) TFR(29) TFR(16) TFR(24)
  x0 += ks2; x1 += k0 + 2u;
  TFR(13) TFR(15) TFR(26) TFR(6)
  x0 += k0; x1 += k1 + 3u;
  TFR(17) TFR(29) TFR(16) TFR(24)
  x0 += k1; x1 += ks2 + 4u;
  TFR(13) TFR(15) TFR(26) TFR(6)
  x0 += ks2; x1 += k0 + 5u;
#undef TFR
  y0 = x0; y1 = x1;
}

__device__ __forceinline__ bool dropout_keep(u32 j) {
  u32 y0, y1;
  threefry2x32(0u, 42u, 0u, j, y0, y1);
  return ((y0 ^ y1) & 0x80000000u) == 0u;
}

// ---------------------------------------------------------------------------
// stage_edges v2: LDS hist -> chunk reservation -> scan -> block-local
// inverse permutation -> COALESCED bucket-sorted writes.
// Output content identical to r12's stage_edges (positions via atomic order).
// ---------------------------------------------------------------------------
__global__ __launch_bounds__(256) void stage_edges(
    const int* __restrict__ src, const int* __restrict__ dst,
    const float* __restrict__ ew, int* __restrict__ bcur,
    int2* __restrict__ staged, int E, int nb) {
  __shared__ int h[512];
  __shared__ int cb[512];        // per-bucket global chunk base (relative)
  __shared__ int lbase[512];     // per-bucket block-local exclusive base
  __shared__ int cur2[512];
  __shared__ int sc[256];
  __shared__ u16 inv[EPB];       // slot (bucket-sorted) -> local edge index
  const int t = threadIdx.x;
  h[t] = 0; h[t + 256] = 0;
  __syncthreads();
  const int base = blockIdx.x * EPB;
  const int end = min(base + EPB, E);
  const int bcnt = end - base;
  // pass 1: histogram
  for (int i = base + t; i < end; i += 256)
    atomicAdd(&h[(u32)dst[i] >> 8], 1);
  __syncthreads();
  // reserve global chunks (one atomic per non-empty bucket)
  for (int j = t; j < nb; j += 256)
    cb[j] = h[j] ? atomicAdd(&bcur[j], h[j]) : 0;
  // exclusive scan of h (512 entries, 2 per thread)
  int a0 = h[2 * t], a1 = h[2 * t + 1];
  int s2 = a0 + a1;
  sc[t] = s2;
  __syncthreads();
  for (int off = 1; off < 256; off <<= 1) {
    int tmp = (t >= off) ? sc[t - off] : 0;
    __syncthreads();
    sc[t] += tmp;
    __syncthreads();
  }
  int excl2 = sc[t] - s2;
  lbase[2 * t] = excl2;       cur2[2 * t] = excl2;
  lbase[2 * t + 1] = excl2 + a0; cur2[2 * t + 1] = excl2 + a0;
  __syncthreads();
  // pass 2: build inverse permutation (dst re-read is L2-hot)
  for (int i = base + t; i < end; i += 256) {
    int b = (u32)dst[i] >> 8;
    int s = atomicAdd(&cur2[b], 1);
    inv[s] = (u16)(i - base);
  }
  __syncthreads();
  // pass 3: coalesced writes in bucket-sorted slot order
  for (int s = t; s < bcnt; s += 256) {
    int j = base + (int)inv[s];
    int d = dst[j];
    int b = (u32)d >> 8;
    int gpos = cb[b] + (s - lbase[b]);   // position within bucket
    if (gpos < CAP)  // overflow guard (never fires for this input)
      staged[(size_t)b * CAP + gpos] =
          make_int2(src[j] | ((d & 255) << 23), __builtin_bit_cast(int, ew[j]));
  }
}

// ---------------------------------------------------------------------------
// bucket_sort v2: one block per 256-node bucket. Bucket copied to LDS once;
// LDS hist + scan -> rowinfo (even/16B-aligned row starts); inverse perm in
// LDS; final epk writes fully COALESCED. Content identical to r12's sort.
// ---------------------------------------------------------------------------
__global__ __launch_bounds__(256) void bucket_sort(
    const int2* __restrict__ staged, const int* __restrict__ bcur,
    int2* __restrict__ rowinfo, int2* __restrict__ epk, int N) {
  __shared__ int2 buf[CAP];        // 38.9 KB: the bucket's staged edges
  __shared__ u16 inv[CAP + 256];   // padded slots included
  __shared__ int cnt[256];
  __shared__ int cur[256];
  __shared__ int sc[256];
  const int t = threadIdx.x;
  const int b = blockIdx.x;
  const int node0 = b << 8;
  const int nn = min(256, N - node0);
  const int ebase = b * CAP;
  const int ecnt = min(bcur[b], CAP);
  cnt[t] = 0;
  __syncthreads();
  // pass 1: copy to LDS + histogram (single global read of staged)
  for (int i = t; i < ecnt; i += 256) {
    int2 p = staged[ebase + i];
    buf[i] = p;
    atomicAdd(&cnt[(u32)p.x >> 23], 1);
  }
  __syncthreads();
  int a = cnt[t];
  int pa = (a + 1) & ~1;  // even-padded length (16B-aligned row starts)
  sc[t] = pa;
  __syncthreads();
  for (int off = 1; off < 256; off <<= 1) {
    int tmp = (t >= off) ? sc[t - off] : 0;
    __syncthreads();
    sc[t] += tmp;
    __syncthreads();
  }
  int excl = sc[t] - pa;
  cur[t] = excl;                       // block-local cursor
  if (a & 1) inv[excl + a] = 0;        // deterministic filler for pad slot
  if (t < nn) rowinfo[node0 + t] = make_int2(ebase + excl, a);
  const int total = sc[255];           // padded total (<= ecnt + 256)
  __syncthreads();
  // pass 2: inverse permutation via LDS atomics
  for (int i = t; i < ecnt; i += 256) {
    int dl = (u32)buf[i].x >> 23;
    int pos = atomicAdd(&cur[dl], 1);
    inv[pos] = (u16)i;
  }
  __syncthreads();
  // pass 3: fully coalesced epk writes
  for (int s = t; s < total; s += 256) {
    int2 p = buf[inv[s]];
    epk[ebase + s] = make_int2(p.x & 0x7fffff, p.y);
  }
}

// ---------------------------------------------------------------------------
// shared FMA helper: 2 edges x 4 bf16 features into a0..a3 (fp32)
// ---------------------------------------------------------------------------
#define F128_FMA2(VA, VB, W0, W1)                      \
  { float w0 = __builtin_bit_cast(float, W0);          \
    float w1 = __builtin_bit_cast(float, W1);          \
    a0 = fmaf(bf2f((VA).x & 0xffffu), w0, a0);         \
    a1 = fmaf(bf2f((VA).x >> 16), w0, a1);             \
    a2 = fmaf(bf2f((VA).y & 0xffffu), w0, a2);         \
    a3 = fmaf(bf2f((VA).y >> 16), w0, a3);             \
    a0 = fmaf(bf2f((VB).x & 0xffffu), w1, a0);         \
    a1 = fmaf(bf2f((VB).x >> 16), w1, a1);             \
    a2 = fmaf(bf2f((VB).y & 0xffffu), w1, a2);         \
    a3 = fmaf(bf2f((VB).y >> 16), w1, a3); }

// ---------------------------------------------------------------------------
// CSR spmm F=128: one node per HALF-wave, 8B/lane gathers, UNROLL 8.
// [verified r7/r12 — 60us @ occ 67%, at random-gather traffic roofline]
// ---------------------------------------------------------------------------
__global__ __launch_bounds__(256) void spmm_csr_f128_bf16(
    const u16* __restrict__ V, const int2* __restrict__ epk,
    const int2* __restrict__ rowinfo, u16* __restrict__ out, int N) {
  int node = blockIdx.x * 8 + (threadIdx.x >> 5);
  if (node >= N) return;
  int l32 = threadIdx.x & 31;
  int2 ri = rowinfo[node];
  int e = ri.x, end = ri.x + ri.y;
  float a0 = 0.f, a1 = 0.f, a2 = 0.f, a3 = 0.f;
  for (; e + 8 <= end; e += 8) {
    int4 pp[4];
#pragma unroll
    for (int k = 0; k < 4; ++k)
      pp[k] = reinterpret_cast<const int4*>(epk + e)[k];
    uint2 v[8];
#pragma unroll
    for (int k = 0; k < 4; ++k) {
      v[2 * k] = reinterpret_cast<const uint2*>(V + (size_t)pp[k].x * 128)[l32];
      v[2 * k + 1] = reinterpret_cast<const uint2*>(V + (size_t)pp[k].z * 128)[l32];
    }
#pragma unroll
    for (int k = 0; k < 4; ++k)
      F128_FMA2(v[2 * k], v[2 * k + 1], pp[k].y, pp[k].w);
  }
  if (e + 4 <= end) {
    int4 pp[2];
#pragma unroll
    for (int k = 0; k < 2; ++k)
      pp[k] = reinterpret_cast<const int4*>(epk + e)[k];
    uint2 v[4];
#pragma unroll
    for (int k = 0; k < 2; ++k) {
      v[2 * k] = reinterpret_cast<const uint2*>(V + (size_t)pp[k].x * 128)[l32];
      v[2 * k + 1] = reinterpret_cast<const uint2*>(V + (size_t)pp[k].z * 128)[l32];
    }
#pragma unroll
    for (int k = 0; k < 2; ++k)
      F128_FMA2(v[2 * k], v[2 * k + 1], pp[k].y, pp[k].w);
    e += 4;
  }
  for (; e < end; ++e) {
    int2 p = epk[e];
    uint2 v = reinterpret_cast<const uint2*>(V + (size_t)p.x * 128)[l32];
    float w = __builtin_bit_cast(float, p.y);
    a0 = fmaf(bf2f(v.x & 0xffffu), w, a0);
    a1 = fmaf(bf2f(v.x >> 16), w, a1);
    a2 = fmaf(bf2f(v.y & 0xffffu), w, a2);
    a3 = fmaf(bf2f(v.y >> 16), w, a3);
  }
  uint2 o;
  o.x = (u32)f2bf(a0) | ((u32)f2bf(a1) << 16);
  o.y = (u32)f2bf(a2) | ((u32)f2bf(a3) << 16);
  reinterpret_cast<uint2*>(out + (size_t)node * 128)[l32] = o;
}

// ---------------------------------------------------------------------------
// CSR spmm F=64: one node per QUARTER-wave (16 lanes x 8B), unroll 8,
// b2 folded into accumulator init.  [verified r7/r12]
// ---------------------------------------------------------------------------
__global__ __launch_bounds__(256) void spmm_csr_f64_bias(
    const u16* __restrict__ V, const int2* __restrict__ epk,
    const int2* __restrict__ rowinfo, const float* __restrict__ b2,
    float* __restrict__ out, int N) {
  int node = blockIdx.x * 16 + (threadIdx.x >> 4);
  if (node >= N) return;
  int l16 = threadIdx.x & 15;
  int2 ri = rowinfo[node];
  int e = ri.x, end = ri.x + ri.y;
  float4 bb = reinterpret_cast<const float4*>(b2)[l16];
  float a0 = bb.x, a1 = bb.y, a2 = bb.z, a3 = bb.w;
  for (; e + 8 <= end; e += 8) {
    int4 pp[4];
#pragma unroll
    for (int k = 0; k < 4; ++k)
      pp[k] = reinterpret_cast<const int4*>(epk + e)[k];
    uint2 v[8];
#pragma unroll
    for (int k = 0; k < 4; ++k) {
      v[2 * k] = reinterpret_cast<const uint2*>(V + (size_t)pp[k].x * 64)[l16];
      v[2 * k + 1] = reinterpret_cast<const uint2*>(V + (size_t)pp[k].z * 64)[l16];
    }
#pragma unroll
    for (int k = 0; k < 4; ++k)
      F128_FMA2(v[2 * k], v[2 * k + 1], pp[k].y, pp[k].w);
  }
  for (; e < end; ++e) {
    int2 p = epk[e];
    uint2 v = reinterpret_cast<const uint2*>(V + (size_t)p.x * 64)[l16];
    float w = __builtin_bit_cast(float, p.y);
    a0 = fmaf(bf2f(v.x & 0xffffu), w, a0);
    a1 = fmaf(bf2f(v.x >> 16), w, a1);
    a2 = fmaf(bf2f(v.y & 0xffffu), w, a2);
    a3 = fmaf(bf2f(v.y >> 16), w, a3);
  }
  reinterpret_cast<float4*>(out + (size_t)node * 64)[l16] =
      make_float4(a0, a1, a2, a3);
}

// ---------------------------------------------------------------------------
// GEMM A (MFMA bf16): y[N,128](bf16) = x @ W1 — verified round 3
// ---------------------------------------------------------------------------
__global__ __launch_bounds__(256) void gemm_xw1_mfma(
    const float* __restrict__ X, const float* __restrict__ W,
    u16* __restrict__ Y, int N) {
  __shared__ short As[128 * 128];
  __shared__ short Bs[128 * 128];
  const int t = threadIdx.x;
  const int row0 = blockIdx.x << 7;

  for (int i = t; i < 128 * 32; i += 256) {
    int m = i >> 5, k4 = i & 31;
    int r = row0 + m;
    float4 v = make_float4(0.f, 0.f, 0.f, 0.f);
    if (r < N) v = reinterpret_cast<const float4*>(X)[(size_t)r * 32 + k4];
    u16x4 b;
    b.x = f2bf(v.x); b.y = f2bf(v.y); b.z = f2bf(v.z); b.w = f2bf(v.w);
    int off = (m * 128 + (k4 << 2)) ^ ((m & 7) << 3);
    *reinterpret_cast<u16x4*>(&As[off]) = b;
  }
  for (int i = t; i < 128 * 32; i += 256) {
    int k = i >> 5, n4 = i & 31;
    float4 v = reinterpret_cast<const float4*>(W)[(size_t)k * 32 + n4];
    int c0 = n4 << 2;
    Bs[(((c0 + 0) * 128 + k)) ^ (((c0 + 0) & 7) << 3)] = (short)f2bf(v.x);
    Bs[(((c0 + 1) * 128 + k)) ^ (((c0 + 1) & 7) << 3)] = (short)f2bf(v.y);
    Bs[(((c0 + 2) * 128 + k)) ^ (((c0 + 2) & 7) << 3)] = (short)f2bf(v.z);
    Bs[(((c0 + 3) * 128 + k)) ^ (((c0 + 3) & 7) << 3)] = (short)f2bf(v.w);
  }
  __syncthreads();

  const int wid = t >> 6, lane = t & 63;
  const int wr = (wid >> 1) * 64, wc = (wid & 1) * 64;
  const int l15 = lane & 15, lk = (lane >> 4) * 8;

  f32x4 acc[4][4];
#pragma unroll
  for (int m = 0; m < 4; ++m)
#pragma unroll
    for (int n = 0; n < 4; ++n) acc[m][n] = (f32x4)(0.f);

#pragma unroll
  for (int kk = 0; kk < 4; ++kk) {
    const int kb = kk * 32 + lk;
    short8 a[4], b[4];
#pragma unroll
    for (int m = 0; m < 4; ++m) {
      int row = wr + m * 16 + l15;
      a[m] = *reinterpret_cast<const short8*>(&As[(row * 128 + kb) ^ ((row & 7) << 3)]);
    }
#pragma unroll
    for (int n = 0; n < 4; ++n) {
      int col = wc + n * 16 + l15;
      b[n] = *reinterpret_cast<const short8*>(&Bs[(col * 128 + kb) ^ ((col & 7) << 3)]);
    }
#pragma unroll
    for (int m = 0; m < 4; ++m)
#pragma unroll
      for (int n = 0; n < 4; ++n)
        acc[m][n] = __builtin_amdgcn_mfma_f32_16x16x32_bf16(a[m], b[n], acc[m][n], 0, 0, 0);
  }

#pragma unroll
  for (int m = 0; m < 4; ++m) {
    int rbase = row0 + wr + m * 16 + (lane >> 4) * 4;
#pragma unroll
    for (int n = 0; n < 4; ++n) {
      int col = wc + n * 16 + l15;
#pragma unroll
      for (int r = 0; r < 4; ++r) {
        int row = rbase + r;
        if (row < N) Y[(size_t)row * 128 + col] = f2bf(acc[m][n][r]);
      }
    }
  }
}

// ---------------------------------------------------------------------------
// GEMM B (MFMA bf16, fused epilogue): h3[N,64] = dropout(relu(h1 + b1)) @ W2
// tile 64x64 (LDS 32KB -> 5 blocks/CU), 4 waves x 16 rows. [verified r9/r12]
// ---------------------------------------------------------------------------
__global__ __launch_bounds__(256) void gemm_h_w2_mfma(
    const u16* __restrict__ H, const float* __restrict__ bias1,
    const float* __restrict__ W2, u16* __restrict__ O, int N) {
  __shared__ short As[64 * 128];  // 16 KB
  __shared__ short Bs[64 * 128];  // 16 KB (transposed: [n][k])
  const int t = threadIdx.x;
  const int row0 = blockIdx.x << 6;

  for (int i = t; i < 128 * 16; i += 256) {
    int k = i >> 4, n4 = i & 15;
    float4 v = reinterpret_cast<const float4*>(W2)[(size_t)k * 16 + n4];
    int c0 = n4 << 2;
    Bs[(((c0 + 0) * 128 + k)) ^ (((c0 + 0) & 7) << 3)] = (short)f2bf(v.x);
    Bs[(((c0 + 1) * 128 + k)) ^ (((c0 + 1) & 7) << 3)] = (short)f2bf(v.y);
    Bs[(((c0 + 2) * 128 + k)) ^ (((c0 + 2) & 7) << 3)] = (short)f2bf(v.z);
    Bs[(((c0 + 3) * 128 + k)) ^ (((c0 + 3) & 7) << 3)] = (short)f2bf(v.w);
  }

  for (int i = t; i < 64 * 16; i += 256) {
    int m = i >> 4, g = i & 15;
    int r = row0 + m;
    int c0 = g << 3;
    u16x8 o = (u16x8)(0);
    if (r < N) {
      u16x8 v = *reinterpret_cast<const u16x8*>(H + (size_t)r * 128 + c0);
      float4 b0 = reinterpret_cast<const float4*>(bias1)[g * 2];
      float4 b1v = reinterpret_cast<const float4*>(bias1)[g * 2 + 1];
      float bb[8] = {b0.x, b0.y, b0.z, b0.w, b1v.x, b1v.y, b1v.z, b1v.w};
      u32 base = (u32)r * 128u + (u32)c0;
#pragma unroll
      for (int e = 0; e < 8; ++e) {
        float z = fmaxf(bf2f((u16)v[e]) + bb[e], 0.f);
        o[e] = dropout_keep(base + e) ? f2bf(z + z) : (u16)0;
      }
    }
    *reinterpret_cast<u16x8*>(&As[(m * 128 + c0) ^ ((m & 7) << 3)]) = o;
  }
  __syncthreads();

  const int wid = t >> 6, lane = t & 63;
  const int wr = wid * 16;
  const int l15 = lane & 15, lk = (lane >> 4) * 8;

  f32x4 acc[4];
#pragma unroll
  for (int n = 0; n < 4; ++n) acc[n] = (f32x4)(0.f);

#pragma unroll
  for (int kk = 0; kk < 4; ++kk) {
    const int kb = kk * 32 + lk;
    int row = wr + l15;
    short8 a = *reinterpret_cast<const short8*>(&As[(row * 128 + kb) ^ ((row & 7) << 3)]);
    short8 b[4];
#pragma unroll
    for (int n = 0; n < 4; ++n) {
      int col = n * 16 + l15;
      b[n] = *reinterpret_cast<const short8*>(&Bs[(col * 128 + kb) ^ ((col & 7) << 3)]);
    }
#pragma unroll
    for (int n = 0; n < 4; ++n)
      acc[n] = __builtin_amdgcn_mfma_f32_16x16x32_bf16(a, b[n], acc[n], 0, 0, 0);
  }

  {
    int rbase = row0 + wr + (lane >> 4) * 4;
#pragma unroll
    for (int n = 0; n < 4; ++n) {
      int col = n * 16 + l15;
#pragma unroll
      for (int r = 0; r < 4; ++r) {
        int row = rbase + r;
        if (row < N) O[(size_t)row * 64 + col] = f2bf(acc[n][r]);
      }
    }
  }
}

// ---------------------------------------------------------------------------
// Pipeline:
//   memset bcur ; stage_edges(v2) ; gemmA ; bucket_sort(v2) ;
//   spmm128 -> h1(bf16) ; gemmB -> h3 ; spmm64(+b2) -> out
// ---------------------------------------------------------------------------
extern "C" void kernel_launch(void* const* d_in, const int* in_sizes, int n_in,
                              void* d_out, int out_size, void* d_ws, size_t ws_size,
                              hipStream_t stream) {
  const float* x  = (const float*)d_in[0];
  const float* ew = (const float*)d_in[1];
  const float* W1 = (const float*)d_in[2];
  const float* b1 = (const float*)d_in[3];
  const float* W2 = (const float*)d_in[4];
  const float* b2 = (const float*)d_in[5];
  const int*   src = (const int*)d_in[6];
  const int*   dst = (const int*)d_in[7];
  const int N = in_sizes[0] / 128;
  const int E = in_sizes[1];
  float* out = (float*)d_out;

  const int nb = (N + 255) >> 8;  // 256-node buckets (391 for N=100000)

  // workspace layout (r12-verified)
  u16*   h1      = (u16*)d_ws;                       // N*128 bf16
  u16*   y       = h1 + (size_t)N * 128;             // N*128 bf16 (reused as h3)
  u16*   h3      = y;
  int2*  staged  = (int2*)(y + (size_t)N * 128);     // nb*CAP * 8B
  int2*  epk     = staged + (size_t)nb * CAP;        // nb*CAP * 8B
  int2*  rowinfo = epk + (size_t)nb * CAP;           // N * 8B
  int*   bcur    = (int*)(rowinfo + N + 4);          // nb (relative cursors)

  const int cBlocks = (E + EPB - 1) / EPB;
  const int gBlocks = (N + 127) / 128;

  hipMemsetAsync(bcur, 0, (size_t)nb * sizeof(int), stream);
  stage_edges<<<cBlocks, 256, 0, stream>>>(src, dst, ew, bcur, staged, E, nb);
  gemm_xw1_mfma<<<gBlocks, 256, 0, stream>>>(x, W1, y, N);
  bucket_sort<<<nb, 256, 0, stream>>>(staged, bcur, rowinfo, epk, N);
  spmm_csr_f128_bf16<<<(N + 7) / 8, 256, 0, stream>>>(y, epk, rowinfo, h1, N);
  gemm_h_w2_mfma<<<(N + 63) / 64, 256, 0, stream>>>(h1, b1, W2, h3, N);
  spmm_csr_f64_bias<<<(N + 15) / 16, 256, 0, stream>>>(h3, epk, rowinfo, b2, out, N);
}